// Round 1
// baseline (3453.003 us; speedup 1.0000x reference)
//
#include <hip/hip_runtime.h>

// MeanShift: N=200000 pts x D=64 fp32, K=256 centers, 10 iterations, bandwidth 12.
// Strategy (round 1, fp32 VALU baseline):
//   - thread-owns-center: block=256 threads, thread k holds center k coords +
//     masked-sum accumulator in VGPRs (~150 VGPRs, launch_bounds(256,2)).
//   - points staged in LDS chunks, broadcast-read by all lanes (conflict-free).
//   - deterministic 2-stage reduction through per-block partials in d_ws.
//   - ping-pong center buffers so the final pass has c9 (mask) and c10 (dist).

#define NPTS   200000
#define DIM    64
#define KC     256
#define ITERS  10
#define BW2    144.0f
#define CHUNK  80            // points per LDS chunk; 200000 = 2500*80 exactly
#define NCHUNKS (NPTS / CHUNK)

__global__ void x2_kernel(const float* __restrict__ x, float* __restrict__ x2) {
    int i = blockIdx.x * 256 + threadIdx.x;
    if (i >= NPTS) return;
    const float4* xi = (const float4*)(x + (size_t)i * DIM);
    float s0 = 0.f, s1 = 0.f, s2 = 0.f, s3 = 0.f;
#pragma unroll
    for (int d = 0; d < DIM / 4; d++) {
        float4 v = xi[d];
        s0 += v.x * v.x; s1 += v.y * v.y; s2 += v.z * v.z; s3 += v.w * v.w;
    }
    x2[i] = (s0 + s1) + (s2 + s3);
}

__global__ void init_kernel(const float* __restrict__ x, const int* __restrict__ seed,
                            float* __restrict__ c) {
    int t = blockIdx.x * 256 + threadIdx.x;   // K*D threads
    int k = t >> 6, d = t & 63;
    int si = seed[k];
    if ((unsigned)si >= NPTS) si = 0;         // crash guard (dtype hedge)
    c[t] = x[(size_t)si * DIM + d];
}

__global__ __launch_bounds__(256, 2)
void accum_kernel(const float* __restrict__ x, const float* __restrict__ x2,
                  const float* __restrict__ centers,
                  float* __restrict__ psums, float* __restrict__ pcnts, int nblocks) {
    __shared__ __align__(16) float xs[CHUNK * DIM];
    __shared__ float x2s[CHUNK];
    const int k = threadIdx.x;

    float c[DIM];
#pragma unroll
    for (int d = 0; d < DIM; d += 4) {
        float4 v = *(const float4*)(centers + k * DIM + d);
        c[d] = v.x; c[d + 1] = v.y; c[d + 2] = v.z; c[d + 3] = v.w;
    }
    float c2 = 0.f;
#pragma unroll
    for (int d = 0; d < DIM; d++) c2 += c[d] * c[d];

    float sum[DIM];
#pragma unroll
    for (int d = 0; d < DIM; d++) sum[d] = 0.f;
    float cnt = 0.f;

    for (int ch = blockIdx.x; ch < NCHUNKS; ch += nblocks) {
        const int base = ch * CHUNK;
        __syncthreads();
        // stage chunk (perfectly linear copy, coalesced float4)
        for (int t = threadIdx.x; t < CHUNK * DIM / 4; t += 256)
            ((float4*)xs)[t] = ((const float4*)(x + (size_t)base * DIM))[t];
        for (int t = threadIdx.x; t < CHUNK; t += 256)
            x2s[t] = x2[base + t];
        __syncthreads();

        for (int i = 0; i < CHUNK; i++) {
            const float* xi = xs + i * DIM;
            float a0 = 0.f, a1 = 0.f, a2 = 0.f, a3 = 0.f;
#pragma unroll
            for (int d = 0; d < DIM; d += 4) {
                float4 v = *(const float4*)(xi + d);
                a0 += c[d] * v.x; a1 += c[d + 1] * v.y;
                a2 += c[d + 2] * v.z; a3 += c[d + 3] * v.w;
            }
            float dist2 = c2 + x2s[i] - 2.f * ((a0 + a1) + (a2 + a3));
            float m = (dist2 < BW2) ? 1.f : 0.f;
            cnt += m;
#pragma unroll
            for (int d = 0; d < DIM; d += 4) {
                float4 v = *(const float4*)(xi + d);
                sum[d]     += m * v.x; sum[d + 1] += m * v.y;
                sum[d + 2] += m * v.z; sum[d + 3] += m * v.w;
            }
        }
    }

    float* ps = psums + (size_t)blockIdx.x * KC * DIM + k * DIM;
#pragma unroll
    for (int d = 0; d < DIM; d += 4) {
        float4 v = { sum[d], sum[d + 1], sum[d + 2], sum[d + 3] };
        *(float4*)(ps + d) = v;
    }
    pcnts[blockIdx.x * KC + k] = cnt;
}

// block = 256 threads = 4 centers x 64 dims; grid = K/4
__global__ void update_kernel(const float* __restrict__ psums, const float* __restrict__ pcnts,
                              float* __restrict__ newc, int nblocks) {
    const int kl = threadIdx.x >> 6;
    const int d  = threadIdx.x & 63;
    const int k  = blockIdx.x * 4 + kl;
    float s = 0.f;
    for (int b = 0; b < nblocks; b++)
        s += psums[(size_t)b * KC * DIM + k * DIM + d];
    float cn = 0.f;
    for (int b = d; b < nblocks; b += 64)
        cn += pcnts[b * KC + k];
#pragma unroll
    for (int off = 32; off > 0; off >>= 1)
        cn += __shfl_down(cn, off, 64);
    cn = __shfl(cn, 0, 64);
    newc[k * DIM + d] = s / cn;
}

// mask from c9 (last_mask), distance to c10; per-block lexicographic best (d2, idx)
__global__ __launch_bounds__(256, 2)
void final_kernel(const float* __restrict__ x, const float* __restrict__ x2,
                  const float* __restrict__ c9, const float* __restrict__ c10,
                  float* __restrict__ fbest, int* __restrict__ fidx, int nblocks) {
    __shared__ __align__(16) float xs[CHUNK * DIM];
    __shared__ float x2s[CHUNK];
    const int k = threadIdx.x;

    float c9r[DIM], c10r[DIM];
#pragma unroll
    for (int d = 0; d < DIM; d += 4) {
        float4 v = *(const float4*)(c9 + k * DIM + d);
        c9r[d] = v.x; c9r[d + 1] = v.y; c9r[d + 2] = v.z; c9r[d + 3] = v.w;
        float4 w = *(const float4*)(c10 + k * DIM + d);
        c10r[d] = w.x; c10r[d + 1] = w.y; c10r[d + 2] = w.z; c10r[d + 3] = w.w;
    }
    float c2_9 = 0.f, c2_10 = 0.f;
#pragma unroll
    for (int d = 0; d < DIM; d++) { c2_9 += c9r[d] * c9r[d]; c2_10 += c10r[d] * c10r[d]; }

    float bestd = INFINITY;
    int   besti = 0x7FFFFFFF;

    for (int ch = blockIdx.x; ch < NCHUNKS; ch += nblocks) {
        const int base = ch * CHUNK;
        __syncthreads();
        for (int t = threadIdx.x; t < CHUNK * DIM / 4; t += 256)
            ((float4*)xs)[t] = ((const float4*)(x + (size_t)base * DIM))[t];
        for (int t = threadIdx.x; t < CHUNK; t += 256)
            x2s[t] = x2[base + t];
        __syncthreads();

        for (int i = 0; i < CHUNK; i++) {
            const float* xi = xs + i * DIM;
            float a0 = 0.f, a1 = 0.f, a2 = 0.f, a3 = 0.f;
            float b0 = 0.f, b1 = 0.f, b2 = 0.f, b3 = 0.f;
#pragma unroll
            for (int d = 0; d < DIM; d += 4) {
                float4 v = *(const float4*)(xi + d);
                a0 += c9r[d] * v.x;  a1 += c9r[d + 1] * v.y;
                a2 += c9r[d + 2] * v.z;  a3 += c9r[d + 3] * v.w;
                b0 += c10r[d] * v.x; b1 += c10r[d + 1] * v.y;
                b2 += c10r[d + 2] * v.z; b3 += c10r[d + 3] * v.w;
            }
            float d2m = c2_9 + x2s[i] - 2.f * ((a0 + a1) + (a2 + a3));   // mask dist (c9)
            if (d2m < BW2) {
                float d2 = c2_10 + x2s[i] - 2.f * ((b0 + b1) + (b2 + b3));
                d2 = fmaxf(d2, 0.f);
                int gi = base + i;
                if (d2 < bestd || (d2 == bestd && gi < besti)) { bestd = d2; besti = gi; }
            }
        }
    }
    fbest[(size_t)blockIdx.x * KC + k] = bestd;
    fidx [(size_t)blockIdx.x * KC + k] = besti;
}

__global__ void output_kernel(const float* __restrict__ x, const float* __restrict__ c10,
                              const float* __restrict__ fbest, const int* __restrict__ fidx,
                              float* __restrict__ out, int nblocks) {
    const int k = threadIdx.x;   // one block of 256
    float bd = INFINITY;
    int   bi = 0x7FFFFFFF;
    for (int b = 0; b < nblocks; b++) {
        float d = fbest[(size_t)b * KC + k];
        int   i = fidx [(size_t)b * KC + k];
        if (d < bd || (d == bd && i < bi)) { bd = d; bi = i; }
    }
    if ((unsigned)bi >= NPTS) bi = 0;   // all-masked-out guard (matches argmin of all-inf)
#pragma unroll
    for (int d = 0; d < DIM; d++) out[k * DIM + d] = c10[k * DIM + d];
#pragma unroll
    for (int d = 0; d < DIM; d++) out[KC * DIM + k * DIM + d] = x[(size_t)bi * DIM + d];
    out[2 * KC * DIM + k] = (float)bi;
}

extern "C" void kernel_launch(void* const* d_in, const int* in_sizes, int n_in,
                              void* d_out, int out_size, void* d_ws, size_t ws_size,
                              hipStream_t stream) {
    const float* x    = (const float*)d_in[0];
    const int*   seed = (const int*)d_in[1];
    float*       out  = (float*)d_out;

    // workspace layout (all 16B aligned)
    char* w = (char*)d_ws;
    float* x2 = (float*)w;  w += (size_t)NPTS * 4;
    float* cA = (float*)w;  w += (size_t)KC * DIM * 4;
    float* cB = (float*)w;  w += (size_t)KC * DIM * 4;

    size_t fixed   = (size_t)NPTS * 4 + 2 * (size_t)KC * DIM * 4;
    size_t per_blk = (size_t)KC * DIM * 4 + 3 * (size_t)KC * 4;  // psums + pcnts + fbest + fidx
    int nb = 1;
    if (ws_size > fixed + per_blk)
        nb = (int)((ws_size - fixed) / per_blk);
    if (nb > 500) nb = 500;   // 500 blocks -> ~2 blocks/CU, 5 chunks each exactly

    float* pcnts = (float*)w;  w += (size_t)nb * KC * 4;
    float* fbest = (float*)w;  w += (size_t)nb * KC * 4;
    int*   fidx  = (int*)w;    w += (size_t)nb * KC * 4;
    float* psums = (float*)w;

    x2_kernel<<<(NPTS + 255) / 256, 256, 0, stream>>>(x, x2);
    init_kernel<<<KC * DIM / 256, 256, 0, stream>>>(x, seed, cA);

    float* cin = cA;
    float* cou = cB;
    for (int it = 0; it < ITERS; it++) {
        accum_kernel<<<nb, 256, 0, stream>>>(x, x2, cin, psums, pcnts, nb);
        update_kernel<<<KC / 4, 256, 0, stream>>>(psums, pcnts, cou, nb);
        float* t = cin; cin = cou; cou = t;
    }
    // after 10 iters: cin == cA holds c10, cB holds c9
    final_kernel<<<nb, 256, 0, stream>>>(x, x2, cB, cA, fbest, fidx, nb);
    output_kernel<<<1, 256, 0, stream>>>(x, cA, fbest, fidx, out, nb);
}

// Round 2
// 910.084 us; speedup vs baseline: 3.7942x; 3.7942x over previous
//
#include <hip/hip_runtime.h>

// MeanShift round 2.
// r1 post-mortem: accum was LDS-broadcast-bound (VALUBusy 19%; 32 ds_read_b128
// per point per wave x 4 waves = 6:1 LDS:VALU). Fix: lane-owns-point structure,
// centers read via wave-uniform loads (s_load path), masked sum replaced by
// fp64 total minus (expected-zero) sparse exclusions; device-side fixed-point
// flag skips converged iterations (bit-exact identical output, safe fallback).

#define NPTS   200000
#define DIM    64
#define KC     256
#define ITERS  10
#define BW2    144.0f
#define CHUNK  80
#define NCHUNKS (NPTS / CHUNK)
#define NB_DENSE 256
#define NW     3125            // 200000 / 64 waves, exact
#define FABLK  782             // ceil(3125/4) blocks of 4 waves

__global__ void x2_kernel(const float* __restrict__ x, float* __restrict__ x2) {
    int i = blockIdx.x * 256 + threadIdx.x;
    if (i >= NPTS) return;
    const float4* xi = (const float4*)(x + (size_t)i * DIM);
    float s0 = 0.f, s1 = 0.f, s2 = 0.f, s3 = 0.f;
#pragma unroll
    for (int d = 0; d < DIM / 4; d++) {
        float4 v = xi[d];
        s0 += v.x * v.x; s1 += v.y * v.y; s2 += v.z * v.z; s3 += v.w * v.w;
    }
    x2[i] = (s0 + s1) + (s2 + s3);
}

__global__ void init_kernel(const float* __restrict__ x, const int* __restrict__ seed,
                            float* __restrict__ c, float* __restrict__ c2) {
    int t = blockIdx.x * 256 + threadIdx.x;   // 16384 threads; wave = one center
    int k = t >> 6, d = t & 63;
    int si = seed[k];
    if ((unsigned)si >= NPTS) si = 0;
    float v = x[(size_t)si * DIM + d];
    c[t] = v;
    float s = v * v;
#pragma unroll
    for (int off = 32; off > 0; off >>= 1) s += __shfl_xor(s, off, 64);
    if (d == 0) c2[k] = s;
}

// fp64 grand total of x per dim: stage 1 -> totpart[512][64]
__global__ void totsum_kernel(const float* __restrict__ x, double* __restrict__ totpart) {
    __shared__ double sd[256];
    const int tid = threadIdx.x;
    double acc = 0.0;
    for (size_t f = (size_t)blockIdx.x * 256 + tid; f < (size_t)NPTS * DIM; f += 512 * 256)
        acc += (double)x[f];          // stride % 64 == 0 -> dim = tid & 63 constant
    sd[tid] = acc;
    __syncthreads();
    if (tid < 64)
        totpart[(size_t)blockIdx.x * 64 + tid] =
            sd[tid] + sd[tid + 64] + sd[tid + 128] + sd[tid + 192];
}

__global__ void totsum2_kernel(const double* __restrict__ totpart, double* __restrict__ total) {
    const int d = threadIdx.x;    // 64 threads
    double acc = 0.0;
    for (int b = 0; b < 512; b++) acc += totpart[(size_t)b * 64 + d];
    total[d] = acc;
}

__global__ void zero_kernel(float* __restrict__ excl_sum, int* __restrict__ excl_cnt,
                            int* __restrict__ mm) {
    int t = blockIdx.x * 256 + threadIdx.x;
    if (t < KC * DIM) excl_sum[t] = 0.f;
    if (t < KC)       excl_cnt[t] = 0;
    if (t < 16)       mm[t] = 0;
}

// ---- iteration 1: dense masked-mean (proven round-1 kernel), nb = 256 ----
__global__ __launch_bounds__(256, 2)
void accum_dense(const float* __restrict__ x, const float* __restrict__ x2,
                 const float* __restrict__ centers,
                 float* __restrict__ psums, float* __restrict__ pcnts) {
    __shared__ __align__(16) float xs[CHUNK * DIM];
    __shared__ float x2s[CHUNK];
    const int k = threadIdx.x;

    float c[DIM];
#pragma unroll
    for (int d = 0; d < DIM; d += 4) {
        float4 v = *(const float4*)(centers + k * DIM + d);
        c[d] = v.x; c[d + 1] = v.y; c[d + 2] = v.z; c[d + 3] = v.w;
    }
    float c2 = 0.f;
#pragma unroll
    for (int d = 0; d < DIM; d++) c2 += c[d] * c[d];

    float sum[DIM];
#pragma unroll
    for (int d = 0; d < DIM; d++) sum[d] = 0.f;
    float cnt = 0.f;

    for (int ch = blockIdx.x; ch < NCHUNKS; ch += NB_DENSE) {
        const int base = ch * CHUNK;
        __syncthreads();
        for (int t = threadIdx.x; t < CHUNK * DIM / 4; t += 256)
            ((float4*)xs)[t] = ((const float4*)(x + (size_t)base * DIM))[t];
        for (int t = threadIdx.x; t < CHUNK; t += 256)
            x2s[t] = x2[base + t];
        __syncthreads();

        for (int i = 0; i < CHUNK; i++) {
            const float* xi = xs + i * DIM;
            float a0 = 0.f, a1 = 0.f, a2 = 0.f, a3 = 0.f;
#pragma unroll
            for (int d = 0; d < DIM; d += 4) {
                float4 v = *(const float4*)(xi + d);
                a0 += c[d] * v.x; a1 += c[d + 1] * v.y;
                a2 += c[d + 2] * v.z; a3 += c[d + 3] * v.w;
            }
            float dist2 = c2 + x2s[i] - 2.f * ((a0 + a1) + (a2 + a3));
            float m = (dist2 < BW2) ? 1.f : 0.f;
            cnt += m;
#pragma unroll
            for (int d = 0; d < DIM; d += 4) {
                float4 v = *(const float4*)(xi + d);
                sum[d]     += m * v.x; sum[d + 1] += m * v.y;
                sum[d + 2] += m * v.z; sum[d + 3] += m * v.w;
            }
        }
    }
    float* ps = psums + (size_t)blockIdx.x * KC * DIM + k * DIM;
#pragma unroll
    for (int d = 0; d < DIM; d += 4) {
        float4 v = { sum[d], sum[d + 1], sum[d + 2], sum[d + 3] };
        *(float4*)(ps + d) = v;
    }
    pcnts[blockIdx.x * KC + k] = cnt;
}

// dense reduce stage A: 512 blocks = 64 kd-groups x 8 b-groups
__global__ void updA_kernel(const float* __restrict__ psums, float* __restrict__ p2) {
    const int g = blockIdx.x >> 3;       // kd group (0..63)
    const int h = blockIdx.x & 7;        // b group  (0..7)
    const int kd = g * 256 + threadIdx.x;
    float s = 0.f;
    for (int b = h * 32; b < h * 32 + 32; b++)
        s += psums[(size_t)b * KC * DIM + kd];
    p2[(size_t)h * KC * DIM + kd] = s;
}

// dense reduce stage B: -> c1, c2_1
__global__ void updB_kernel(const float* __restrict__ p2, const float* __restrict__ pcnts,
                            float* __restrict__ newc, float* __restrict__ newc2) {
    const int kd = blockIdx.x * 256 + threadIdx.x;
    const int k = kd >> 6, d = kd & 63;
    float s = 0.f;
#pragma unroll
    for (int h = 0; h < 8; h++) s += p2[(size_t)h * KC * DIM + kd];
    float cn = 0.f;
    for (int b = d; b < NB_DENSE; b += 64) cn += pcnts[b * KC + k];
#pragma unroll
    for (int off = 32; off > 0; off >>= 1) cn += __shfl_xor(cn, off, 64);
    float c = s / cn;
    newc[kd] = c;
    float q = c * c;
#pragma unroll
    for (int off = 32; off > 0; off >>= 1) q += __shfl_xor(q, off, 64);
    if (d == 0) newc2[k] = q;
}

// ---- iterations 2..10: lane-owns-point, uniform center loads ----
__global__ __launch_bounds__(256, 2)
void accum_fast(const float* __restrict__ x, const float* __restrict__ x2,
                const float* __restrict__ cen, const float* __restrict__ c2,
                float* __restrict__ excl_sum, int* __restrict__ excl_cnt,
                const int* __restrict__ mm_prev, int always_run) {
    if (!always_run && mm_prev[0] == 0) return;   // bit-exact fixed point reached
    const int wave = blockIdx.x * 4 + (threadIdx.x >> 6);
    if (wave >= NW) return;
    const int lane = threadIdx.x & 63;
    const int idx = wave * 64 + lane;

    float px[DIM];
    const float4* xr = (const float4*)(x + (size_t)idx * DIM);
#pragma unroll
    for (int q = 0; q < 16; q++) {
        float4 v = xr[q];
        px[4 * q] = v.x; px[4 * q + 1] = v.y; px[4 * q + 2] = v.z; px[4 * q + 3] = v.w;
    }
    const float x2v = x2[idx];

    for (int k = 0; k < KC; k++) {
        const float* C = cen + k * DIM;          // wave-uniform address -> s_load
        float a0 = 0.f, a1 = 0.f, a2 = 0.f, a3 = 0.f;
#pragma unroll
        for (int d = 0; d < DIM; d += 4) {
            a0 = fmaf(C[d],     px[d],     a0);
            a1 = fmaf(C[d + 1], px[d + 1], a1);
            a2 = fmaf(C[d + 2], px[d + 2], a2);
            a3 = fmaf(C[d + 3], px[d + 3], a3);
        }
        float d2 = x2v + c2[k] - 2.f * ((a0 + a1) + (a2 + a3));
        bool excl = !(d2 < BW2);
        if (__ballot(excl) != 0ull) {            // expected never after iter 1
            if (excl) {
                atomicAdd(&excl_cnt[k], 1);
#pragma unroll 4
                for (int d = 0; d < DIM; d++) atomicAdd(&excl_sum[k * DIM + d], px[d]);
            }
        }
    }
}

__global__ void update_fast(const double* __restrict__ total,
                            float* __restrict__ excl_sum, int* __restrict__ excl_cnt,
                            const float* __restrict__ cin,
                            float* __restrict__ cout, float* __restrict__ c2out,
                            int* __restrict__ mm_out) {
    const int kd = blockIdx.x * 256 + threadIdx.x;   // 64 blocks; wave = one center
    const int k = kd >> 6, d = kd & 63;
    const float ex = excl_sum[kd];
    const int cn = excl_cnt[k];
    const float cnew = (float)((total[d] - (double)ex) / (double)(NPTS - cn));
    cout[kd] = cnew;
    float q = cnew * cnew;
#pragma unroll
    for (int off = 32; off > 0; off >>= 1) q += __shfl_xor(q, off, 64);
    if (d == 0) c2out[k] = q;
    // reset exclusion buffers for the next iteration
    excl_sum[kd] = 0.f;
    if (d == 0) excl_cnt[k] = 0;
    // fixed-point detection (bitwise)
    bool same = (__float_as_uint(cnew) == __float_as_uint(cin[kd]));
    unsigned long long bl = __ballot(!same);
    if (d == 0 && (bl != 0ull || cn != 0)) atomicOr(mm_out, 1);
}

// final: mask from c9, distance to c10, per-wave lexicographic argmin
__global__ __launch_bounds__(256, 2)
void final_kernel(const float* __restrict__ x, const float* __restrict__ x2,
                  const float* __restrict__ c9, const float* __restrict__ c29,
                  const float* __restrict__ c10, const float* __restrict__ c210,
                  float* __restrict__ dbest, int* __restrict__ ibest) {
    const int wave = blockIdx.x * 4 + (threadIdx.x >> 6);
    if (wave >= NW) return;
    const int lane = threadIdx.x & 63;
    const int idx = wave * 64 + lane;

    float px[DIM];
    const float4* xr = (const float4*)(x + (size_t)idx * DIM);
#pragma unroll
    for (int q = 0; q < 16; q++) {
        float4 v = xr[q];
        px[4 * q] = v.x; px[4 * q + 1] = v.y; px[4 * q + 2] = v.z; px[4 * q + 3] = v.w;
    }
    const float x2v = x2[idx];

    float db[4];
    int   ib[4];
    for (int k = 0; k < KC; k++) {
        const float* A = c9  + k * DIM;
        const float* B = c10 + k * DIM;
        float a0 = 0.f, a1 = 0.f, a2 = 0.f, a3 = 0.f;
        float b0 = 0.f, b1 = 0.f, b2 = 0.f, b3 = 0.f;
#pragma unroll
        for (int d = 0; d < DIM; d += 4) {
            a0 = fmaf(A[d],     px[d],     a0);
            a1 = fmaf(A[d + 1], px[d + 1], a1);
            a2 = fmaf(A[d + 2], px[d + 2], a2);
            a3 = fmaf(A[d + 3], px[d + 3], a3);
            b0 = fmaf(B[d],     px[d],     b0);
            b1 = fmaf(B[d + 1], px[d + 1], b1);
            b2 = fmaf(B[d + 2], px[d + 2], b2);
            b3 = fmaf(B[d + 3], px[d + 3], b3);
        }
        float d9 = x2v + c29[k] - 2.f * ((a0 + a1) + (a2 + a3));
        float dd = x2v + c210[k] - 2.f * ((b0 + b1) + (b2 + b3));
        dd = fmaxf(dd, 0.f);
        float cand = (d9 < BW2) ? dd : INFINITY;
        float m = cand;
#pragma unroll
        for (int off = 32; off > 0; off >>= 1) m = fminf(m, __shfl_xor(m, off, 64));
        unsigned long long bl = __ballot(cand == m);
        int sl = __ffsll(bl) - 1;          // lowest lane -> lowest index (numpy tie rule)
        int gi = wave * 64 + sl;
        int qq = k >> 6;
        if ((k & 63) == lane) { db[qq] = m; ib[qq] = gi; }
    }
#pragma unroll
    for (int q = 0; q < 4; q++) {
        dbest[(size_t)wave * KC + q * 64 + lane] = db[q];
        ibest[(size_t)wave * KC + q * 64 + lane] = ib[q];
    }
}

__global__ void combine_kernel(const float* __restrict__ x, const float* __restrict__ c10,
                               const float* __restrict__ dbest, const int* __restrict__ ibest,
                               float* __restrict__ out) {
    __shared__ float sd[256];
    __shared__ int   si[256];
    const int k = blockIdx.x;
    const int t = threadIdx.x;
    float bd = INFINITY;
    int   bi = 0x7FFFFFFF;
    for (int w = t; w < NW; w += 256) {
        float d = dbest[(size_t)w * KC + k];
        int   i = ibest[(size_t)w * KC + k];
        if (d < bd || (d == bd && i < bi)) { bd = d; bi = i; }
    }
    sd[t] = bd; si[t] = bi;
    __syncthreads();
    for (int s = 128; s > 0; s >>= 1) {
        if (t < s) {
            float d = sd[t + s]; int i = si[t + s];
            if (d < sd[t] || (d == sd[t] && i < si[t])) { sd[t] = d; si[t] = i; }
        }
        __syncthreads();
    }
    bi = si[0];
    if ((unsigned)bi >= NPTS) bi = 0;
    if (t < DIM) {
        out[k * DIM + t] = c10[k * DIM + t];
        out[KC * DIM + k * DIM + t] = x[(size_t)bi * DIM + t];
    }
    if (t == 0) out[2 * KC * DIM + k] = (float)bi;
}

extern "C" void kernel_launch(void* const* d_in, const int* in_sizes, int n_in,
                              void* d_out, int out_size, void* d_ws, size_t ws_size,
                              hipStream_t stream) {
    const float* x    = (const float*)d_in[0];
    const int*   seed = (const int*)d_in[1];
    float*       out  = (float*)d_out;

    // workspace layout (512B-aligned slices, ~25.2 MB total)
    char* w = (char*)d_ws;
    auto take = [&](size_t bytes) { char* p = w; w += (bytes + 511) & ~(size_t)511; return p; };
    float*  x2       = (float*)take((size_t)NPTS * 4);
    float*  cA       = (float*)take((size_t)KC * DIM * 4);
    float*  cB       = (float*)take((size_t)KC * DIM * 4);
    float*  c2A      = (float*)take((size_t)KC * 4);
    float*  c2B      = (float*)take((size_t)KC * 4);
    double* total    = (double*)take((size_t)DIM * 8);
    double* totpart  = (double*)take((size_t)512 * DIM * 8);
    float*  psums    = (float*)take((size_t)NB_DENSE * KC * DIM * 4);
    float*  pcnts    = (float*)take((size_t)NB_DENSE * KC * 4);
    float*  p2       = (float*)take((size_t)8 * KC * DIM * 4);
    float*  excl_sum = (float*)take((size_t)KC * DIM * 4);
    int*    excl_cnt = (int*)take((size_t)KC * 4);
    int*    mm       = (int*)take((size_t)16 * 4);
    float*  dbest    = (float*)take((size_t)NW * KC * 4);
    int*    ibest    = (int*)take((size_t)NW * KC * 4);

    x2_kernel<<<(NPTS + 255) / 256, 256, 0, stream>>>(x, x2);
    init_kernel<<<KC * DIM / 256, 256, 0, stream>>>(x, seed, cA, c2A);
    totsum_kernel<<<512, 256, 0, stream>>>(x, totpart);
    totsum2_kernel<<<1, 64, 0, stream>>>(totpart, total);
    zero_kernel<<<64, 256, 0, stream>>>(excl_sum, excl_cnt, mm);

    // iteration 1 (dense; ~21% of points excluded for seed centers)
    accum_dense<<<NB_DENSE, 256, 0, stream>>>(x, x2, cA, psums, pcnts);
    updA_kernel<<<512, 256, 0, stream>>>(psums, p2);
    updB_kernel<<<64, 256, 0, stream>>>(p2, pcnts, cB, c2B);

    // iterations 2..10 (sparse-exclusion fast path + fixed-point skip)
    float *cin = cB, *cou = cA, *c2in = c2B, *c2ou = c2A;
    for (int j = 2; j <= ITERS; j++) {
        accum_fast<<<FABLK, 256, 0, stream>>>(x, x2, cin, c2in, excl_sum, excl_cnt,
                                              mm + (j - 1), (j == 2) ? 1 : 0);
        update_fast<<<64, 256, 0, stream>>>(total, excl_sum, excl_cnt, cin, cou, c2ou, mm + j);
        float* t1 = cin; cin = cou; cou = t1;
        float* t2 = c2in; c2in = c2ou; c2ou = t2;
    }
    // cin = c10, cou = c9 (input of iteration 10)
    final_kernel<<<FABLK, 256, 0, stream>>>(x, x2, cou, c2ou, cin, c2in, dbest, ibest);
    combine_kernel<<<KC, 256, 0, stream>>>(x, cin, dbest, ibest, out);
}

// Round 3
// 809.188 us; speedup vs baseline: 4.2672x; 1.1247x over previous
//
#include <hip/hip_runtime.h>

// MeanShift round 3.
// r2 post-mortem: final_kernel (308us) was scalar-load + shuffle-reduce bound;
// accum_fast j=2,3 ran full (~300us). Fixes:
//  (a) screen trick: |x| + max|c| < 12 proves a point is inside EVERY center's
//      window -> one x2 compare per point replaces the N*K*D GEMM for iters
//      2..10; suspicious points (expected 0) take an inline exact fp32 path.
//  (b) uniform-center check: if all c9 rows / c10 rows are bitwise identical
//      (empirically true from iter 2: centers = total/N), final argmin is a
//      single-center streaming pass (~15us). r2 exact final kept, gated.
//  (c) accum_dense: 512-thr blocks (2 thr/center, 8 waves/CU) + prev-point
//      register trick (each LDS float4 read once: masked-add of pt i-1 + dot
//      of pt i) -> halves LDS broadcast traffic.

#define NPTS   200000
#define DIM    64
#define KC     256
#define ITERS  10
#define BW2    144.0f
#define CHUNK  80
#define NCHUNKS (NPTS / CHUNK)
#define NB_DENSE 256
#define NW     3125            // 200000 / 64 waves
#define FABLK  782

__global__ void x2_kernel(const float* __restrict__ x, float* __restrict__ x2) {
    int i = blockIdx.x * 256 + threadIdx.x;
    if (i >= NPTS) return;
    const float4* xi = (const float4*)(x + (size_t)i * DIM);
    float s0 = 0.f, s1 = 0.f, s2 = 0.f, s3 = 0.f;
#pragma unroll
    for (int d = 0; d < DIM / 4; d++) {
        float4 v = xi[d];
        s0 += v.x * v.x; s1 += v.y * v.y; s2 += v.z * v.z; s3 += v.w * v.w;
    }
    x2[i] = (s0 + s1) + (s2 + s3);
}

__global__ void init_kernel(const float* __restrict__ x, const int* __restrict__ seed,
                            float* __restrict__ c, float* __restrict__ c2) {
    int t = blockIdx.x * 256 + threadIdx.x;
    int k = t >> 6, d = t & 63;
    int si = seed[k];
    if ((unsigned)si >= NPTS) si = 0;
    float v = x[(size_t)si * DIM + d];
    c[t] = v;
    float s = v * v;
#pragma unroll
    for (int off = 32; off > 0; off >>= 1) s += __shfl_xor(s, off, 64);
    if (d == 0) c2[k] = s;
}

__global__ void totsum_kernel(const float* __restrict__ x, double* __restrict__ totpart) {
    __shared__ double sd[256];
    const int tid = threadIdx.x;
    double acc = 0.0;
    for (size_t f = (size_t)blockIdx.x * 256 + tid; f < (size_t)NPTS * DIM; f += 512 * 256)
        acc += (double)x[f];
    sd[tid] = acc;
    __syncthreads();
    if (tid < 64)
        totpart[(size_t)blockIdx.x * 64 + tid] =
            sd[tid] + sd[tid + 64] + sd[tid + 128] + sd[tid + 192];
}

__global__ void totsum2_kernel(const double* __restrict__ totpart, double* __restrict__ total) {
    const int d = threadIdx.x;
    double acc = 0.0;
    for (int b = 0; b < 512; b++) acc += totpart[(size_t)b * 64 + d];
    total[d] = acc;
}

__global__ void zero_kernel(float* __restrict__ excl_sum, int* __restrict__ excl_cnt,
                            unsigned* __restrict__ cmaxbits) {
    int t = blockIdx.x * 256 + threadIdx.x;
    if (t < KC * DIM) excl_sum[t] = 0.f;
    if (t < KC)       excl_cnt[t] = 0;
    if (t < 16)       cmaxbits[t] = 0u;
}

// ---- iteration 1: dense masked mean. 512 thr = 2 thr/center ----
__global__ __launch_bounds__(512, 2)
void accum_dense(const float* __restrict__ x, const float* __restrict__ x2,
                 const float* __restrict__ centers,
                 float* __restrict__ psums, float* __restrict__ pcnts) {
    __shared__ __align__(16) float xs[CHUNK * DIM];   // 20480 B, reused for merge
    __shared__ float x2s[CHUNK];
    const int tid  = threadIdx.x;
    const int k    = tid & 255;
    const int half = tid >> 8;

    float c[DIM];
#pragma unroll
    for (int d = 0; d < DIM; d += 4) {
        float4 v = *(const float4*)(centers + k * DIM + d);
        c[d] = v.x; c[d + 1] = v.y; c[d + 2] = v.z; c[d + 3] = v.w;
    }
    float c2 = 0.f;
#pragma unroll
    for (int d = 0; d < DIM; d++) c2 += c[d] * c[d];

    float sum[DIM], P[DIM];
#pragma unroll
    for (int d = 0; d < DIM; d++) { sum[d] = 0.f; P[d] = 0.f; }
    float cnt = 0.f, mp = 0.f;

    for (int ch = blockIdx.x; ch < NCHUNKS; ch += NB_DENSE) {
        const int base = ch * CHUNK;
        __syncthreads();
        for (int t = tid; t < CHUNK * DIM / 4; t += 512)
            ((float4*)xs)[t] = ((const float4*)(x + (size_t)base * DIM))[t];
        for (int t = tid; t < CHUNK; t += 512)
            x2s[t] = x2[base + t];
        __syncthreads();

        for (int i = half; i < CHUNK; i += 2) {
            const float4* xi = (const float4*)(xs + i * DIM);
            float a0 = 0.f, a1 = 0.f, a2 = 0.f, a3 = 0.f;
#pragma unroll
            for (int q = 0; q < 16; q++) {
                float4 v = xi[q];
                // masked add of previous point (reads P before overwrite)
                sum[4 * q]     += mp * P[4 * q];
                sum[4 * q + 1] += mp * P[4 * q + 1];
                sum[4 * q + 2] += mp * P[4 * q + 2];
                sum[4 * q + 3] += mp * P[4 * q + 3];
                P[4 * q] = v.x; P[4 * q + 1] = v.y; P[4 * q + 2] = v.z; P[4 * q + 3] = v.w;
                a0 += c[4 * q] * v.x;     a1 += c[4 * q + 1] * v.y;
                a2 += c[4 * q + 2] * v.z; a3 += c[4 * q + 3] * v.w;
            }
            float dist2 = c2 + x2s[i] - 2.f * ((a0 + a1) + (a2 + a3));
            mp = (dist2 < BW2) ? 1.f : 0.f;
            cnt += mp;
        }
    }
    // flush pending point
#pragma unroll
    for (int d = 0; d < DIM; d++) sum[d] += mp * P[d];

    // merge half 1 into half 0 through LDS (stride 17 to kill bank conflicts)
    __syncthreads();
#pragma unroll 1
    for (int g = 0; g < 4; g++) {
        if (half == 1) {
#pragma unroll
            for (int j = 0; j < 16; j++) xs[k * 17 + j] = sum[g * 16 + j];
            if (g == 0) xs[4352 + k] = cnt;
        }
        __syncthreads();
        if (half == 0) {
#pragma unroll
            for (int j = 0; j < 16; j++) sum[g * 16 + j] += xs[k * 17 + j];
            if (g == 0) cnt += xs[4352 + k];
        }
        __syncthreads();
    }

    if (half == 0) {
        float* ps = psums + (size_t)blockIdx.x * KC * DIM + k * DIM;
#pragma unroll
        for (int d = 0; d < DIM; d += 4) {
            float4 v = { sum[d], sum[d + 1], sum[d + 2], sum[d + 3] };
            *(float4*)(ps + d) = v;
        }
        pcnts[blockIdx.x * KC + k] = cnt;
    }
}

__global__ void updA_kernel(const float* __restrict__ psums, float* __restrict__ p2) {
    const int g = blockIdx.x >> 3;
    const int h = blockIdx.x & 7;
    const int kd = g * 256 + threadIdx.x;
    float s = 0.f;
    for (int b = h * 32; b < h * 32 + 32; b++)
        s += psums[(size_t)b * KC * DIM + kd];
    p2[(size_t)h * KC * DIM + kd] = s;
}

__global__ void updB_kernel(const float* __restrict__ p2, const float* __restrict__ pcnts,
                            float* __restrict__ newc, float* __restrict__ newc2,
                            unsigned* __restrict__ cmax_out) {
    const int kd = blockIdx.x * 256 + threadIdx.x;
    const int k = kd >> 6, d = kd & 63;
    float s = 0.f;
#pragma unroll
    for (int h = 0; h < 8; h++) s += p2[(size_t)h * KC * DIM + kd];
    float cn = 0.f;
    for (int b = d; b < NB_DENSE; b += 64) cn += pcnts[b * KC + k];
#pragma unroll
    for (int off = 32; off > 0; off >>= 1) cn += __shfl_xor(cn, off, 64);
    float c = s / cn;
    newc[kd] = c;
    float q = c * c;
#pragma unroll
    for (int off = 32; off > 0; off >>= 1) q += __shfl_xor(q, off, 64);
    if (d == 0) { newc2[k] = q; atomicMax(cmax_out, __float_as_uint(q)); }
}

// ---- iters 2..10: screen (1 compare/point); inline exact fallback ----
__global__ void screen_kernel(const float* __restrict__ x, const float* __restrict__ x2,
                              const float* __restrict__ cen, const float* __restrict__ c2,
                              const unsigned* __restrict__ cmaxbits,
                              float* __restrict__ excl_sum, int* __restrict__ excl_cnt) {
    int i = blockIdx.x * 256 + threadIdx.x;
    if (i >= NPTS) return;
    float cm = sqrtf(__uint_as_float(cmaxbits[0]));
    float r = 12.0f - cm - 1e-3f;
    float thr = (r > 0.f) ? r * r : -1.f;
    float x2v = x2[i];
    if (x2v < thr) return;     // |x|+max|c| < 12  =>  inside every window
    // rare exact path (expected never)
    float px[DIM];
    const float4* xr = (const float4*)(x + (size_t)i * DIM);
#pragma unroll
    for (int q = 0; q < 16; q++) {
        float4 v = xr[q];
        px[4 * q] = v.x; px[4 * q + 1] = v.y; px[4 * q + 2] = v.z; px[4 * q + 3] = v.w;
    }
    for (int k = 0; k < KC; k++) {
        const float* C = cen + k * DIM;
        float a0 = 0.f, a1 = 0.f, a2 = 0.f, a3 = 0.f;
#pragma unroll
        for (int d = 0; d < DIM; d += 4) {
            a0 = fmaf(C[d],     px[d],     a0);
            a1 = fmaf(C[d + 1], px[d + 1], a1);
            a2 = fmaf(C[d + 2], px[d + 2], a2);
            a3 = fmaf(C[d + 3], px[d + 3], a3);
        }
        float d2 = x2v + c2[k] - 2.f * ((a0 + a1) + (a2 + a3));
        if (!(d2 < BW2)) {
            atomicAdd(&excl_cnt[k], 1);
#pragma unroll 4
            for (int d = 0; d < DIM; d++) atomicAdd(&excl_sum[k * DIM + d], px[d]);
        }
    }
}

__global__ void update_mean(const double* __restrict__ total,
                            float* __restrict__ excl_sum, int* __restrict__ excl_cnt,
                            float* __restrict__ cout, float* __restrict__ c2out,
                            unsigned* __restrict__ cmax_out) {
    const int kd = blockIdx.x * 256 + threadIdx.x;
    const int k = kd >> 6, d = kd & 63;
    const float ex = excl_sum[kd];
    const int cn = excl_cnt[k];
    const float cnew = (float)((total[d] - (double)ex) / (double)(NPTS - cn));
    cout[kd] = cnew;
    float q = cnew * cnew;
#pragma unroll
    for (int off = 32; off > 0; off >>= 1) q += __shfl_xor(q, off, 64);
    if (d == 0) { c2out[k] = q; atomicMax(cmax_out, __float_as_uint(q)); }
    excl_sum[kd] = 0.f;
    if (d == 0) excl_cnt[k] = 0;
}

// ---- final ----
__global__ void ucheck_kernel(const float* __restrict__ c9, const float* __restrict__ c10,
                              int* __restrict__ uflag) {
    __shared__ int bad;
    const int k = threadIdx.x;     // 256
    if (k == 0) bad = 0;
    __syncthreads();
    bool ok = true;
    for (int d = 0; d < DIM; d++) {
        ok &= (__float_as_uint(c9[k * DIM + d])  == __float_as_uint(c9[d]));
        ok &= (__float_as_uint(c10[k * DIM + d]) == __float_as_uint(c10[d]));
    }
    if (!ok) atomicOr(&bad, 1);
    __syncthreads();
    if (k == 0) uflag[0] = bad ? 0 : 1;
}

__global__ __launch_bounds__(256, 2)
void final_fast(const float* __restrict__ x, const float* __restrict__ x2,
                const float* __restrict__ c9, const float* __restrict__ c29,
                const float* __restrict__ c10, const float* __restrict__ c210,
                const int* __restrict__ uflag,
                float* __restrict__ dbest, int* __restrict__ ibest) {
    if (uflag[0] == 0) return;
    __shared__ __align__(16) float s9[DIM], s10[DIM];
    __shared__ float sc[2];
    const int tid = threadIdx.x;
    if (tid < 64) s9[tid] = c9[tid];
    else if (tid < 128) s10[tid - 64] = c10[tid - 64];
    else if (tid == 128) sc[0] = c29[0];
    else if (tid == 129) sc[1] = c210[0];
    __syncthreads();

    const int i = blockIdx.x * 256 + tid;
    const bool valid = (i < NPTS);
    const int ii = valid ? i : 0;
    const float4* xr = (const float4*)(x + (size_t)ii * DIM);
    float a0 = 0.f, a1 = 0.f, a2 = 0.f, a3 = 0.f;
    float b0 = 0.f, b1 = 0.f, b2 = 0.f, b3 = 0.f;
#pragma unroll
    for (int q = 0; q < 16; q++) {
        float4 v = xr[q];
        float4 u9  = ((const float4*)s9)[q];
        float4 u10 = ((const float4*)s10)[q];
        a0 = fmaf(u9.x, v.x, a0);  a1 = fmaf(u9.y, v.y, a1);
        a2 = fmaf(u9.z, v.z, a2);  a3 = fmaf(u9.w, v.w, a3);
        b0 = fmaf(u10.x, v.x, b0); b1 = fmaf(u10.y, v.y, b1);
        b2 = fmaf(u10.z, v.z, b2); b3 = fmaf(u10.w, v.w, b3);
    }
    const float x2v = x2[ii];
    float d9 = x2v + sc[0] - 2.f * ((a0 + a1) + (a2 + a3));
    float dd = fmaxf(x2v + sc[1] - 2.f * ((b0 + b1) + (b2 + b3)), 0.f);
    float cand = (valid && d9 < BW2) ? dd : INFINITY;

    float m = cand;
#pragma unroll
    for (int off = 32; off > 0; off >>= 1) m = fminf(m, __shfl_xor(m, off, 64));
    unsigned long long bl = __ballot(cand == m);
    int sl = __ffsll(bl) - 1;
    int gi = (blockIdx.x * 256 + (tid & ~63)) + sl;   // lowest index achieving m

    const int gw = blockIdx.x * 4 + (tid >> 6);
    const int lane = tid & 63;
    if (gw < NW) {
#pragma unroll
        for (int q = 0; q < 4; q++) {
            dbest[(size_t)gw * KC + q * 64 + lane] = m;
            ibest[(size_t)gw * KC + q * 64 + lane] = gi;
        }
    }
}

__global__ __launch_bounds__(256, 2)
void final_slow(const float* __restrict__ x, const float* __restrict__ x2,
                const float* __restrict__ c9, const float* __restrict__ c29,
                const float* __restrict__ c10, const float* __restrict__ c210,
                const int* __restrict__ uflag,
                float* __restrict__ dbest, int* __restrict__ ibest) {
    if (uflag[0] != 0) return;
    const int wave = blockIdx.x * 4 + (threadIdx.x >> 6);
    if (wave >= NW) return;
    const int lane = threadIdx.x & 63;
    const int idx = wave * 64 + lane;

    float px[DIM];
    const float4* xr = (const float4*)(x + (size_t)idx * DIM);
#pragma unroll
    for (int q = 0; q < 16; q++) {
        float4 v = xr[q];
        px[4 * q] = v.x; px[4 * q + 1] = v.y; px[4 * q + 2] = v.z; px[4 * q + 3] = v.w;
    }
    const float x2v = x2[idx];

    float db[4];
    int   ib[4];
    for (int k = 0; k < KC; k++) {
        const float* A = c9  + k * DIM;
        const float* B = c10 + k * DIM;
        float a0 = 0.f, a1 = 0.f, a2 = 0.f, a3 = 0.f;
        float b0 = 0.f, b1 = 0.f, b2 = 0.f, b3 = 0.f;
#pragma unroll
        for (int d = 0; d < DIM; d += 4) {
            a0 = fmaf(A[d],     px[d],     a0);
            a1 = fmaf(A[d + 1], px[d + 1], a1);
            a2 = fmaf(A[d + 2], px[d + 2], a2);
            a3 = fmaf(A[d + 3], px[d + 3], a3);
            b0 = fmaf(B[d],     px[d],     b0);
            b1 = fmaf(B[d + 1], px[d + 1], b1);
            b2 = fmaf(B[d + 2], px[d + 2], b2);
            b3 = fmaf(B[d + 3], px[d + 3], b3);
        }
        float d9 = x2v + c29[k] - 2.f * ((a0 + a1) + (a2 + a3));
        float dd = x2v + c210[k] - 2.f * ((b0 + b1) + (b2 + b3));
        dd = fmaxf(dd, 0.f);
        float cand = (d9 < BW2) ? dd : INFINITY;
        float m = cand;
#pragma unroll
        for (int off = 32; off > 0; off >>= 1) m = fminf(m, __shfl_xor(m, off, 64));
        unsigned long long bl = __ballot(cand == m);
        int sl = __ffsll(bl) - 1;
        int gi = wave * 64 + sl;
        int qq = k >> 6;
        if ((k & 63) == lane) { db[qq] = m; ib[qq] = gi; }
    }
#pragma unroll
    for (int q = 0; q < 4; q++) {
        dbest[(size_t)wave * KC + q * 64 + lane] = db[q];
        ibest[(size_t)wave * KC + q * 64 + lane] = ib[q];
    }
}

__global__ void combine_kernel(const float* __restrict__ x, const float* __restrict__ c10,
                               const float* __restrict__ dbest, const int* __restrict__ ibest,
                               float* __restrict__ out) {
    __shared__ float sd[256];
    __shared__ int   si[256];
    const int k = blockIdx.x;
    const int t = threadIdx.x;
    float bd = INFINITY;
    int   bi = 0x7FFFFFFF;
    for (int w = t; w < NW; w += 256) {
        float d = dbest[(size_t)w * KC + k];
        int   i = ibest[(size_t)w * KC + k];
        if (d < bd || (d == bd && i < bi)) { bd = d; bi = i; }
    }
    sd[t] = bd; si[t] = bi;
    __syncthreads();
    for (int s = 128; s > 0; s >>= 1) {
        if (t < s) {
            float d = sd[t + s]; int i = si[t + s];
            if (d < sd[t] || (d == sd[t] && i < si[t])) { sd[t] = d; si[t] = i; }
        }
        __syncthreads();
    }
    bi = si[0];
    if ((unsigned)bi >= NPTS) bi = 0;
    if (t < DIM) {
        out[k * DIM + t] = c10[k * DIM + t];
        out[KC * DIM + k * DIM + t] = x[(size_t)bi * DIM + t];
    }
    if (t == 0) out[2 * KC * DIM + k] = (float)bi;
}

extern "C" void kernel_launch(void* const* d_in, const int* in_sizes, int n_in,
                              void* d_out, int out_size, void* d_ws, size_t ws_size,
                              hipStream_t stream) {
    const float* x    = (const float*)d_in[0];
    const int*   seed = (const int*)d_in[1];
    float*       out  = (float*)d_out;

    char* w = (char*)d_ws;
    auto take = [&](size_t bytes) { char* p = w; w += (bytes + 511) & ~(size_t)511; return p; };
    float*    x2       = (float*)take((size_t)NPTS * 4);
    float*    cA       = (float*)take((size_t)KC * DIM * 4);
    float*    cB       = (float*)take((size_t)KC * DIM * 4);
    float*    c2A      = (float*)take((size_t)KC * 4);
    float*    c2B      = (float*)take((size_t)KC * 4);
    double*   total    = (double*)take((size_t)DIM * 8);
    double*   totpart  = (double*)take((size_t)512 * DIM * 8);
    float*    psums    = (float*)take((size_t)NB_DENSE * KC * DIM * 4);
    float*    pcnts    = (float*)take((size_t)NB_DENSE * KC * 4);
    float*    p2       = (float*)take((size_t)8 * KC * DIM * 4);
    float*    excl_sum = (float*)take((size_t)KC * DIM * 4);
    int*      excl_cnt = (int*)take((size_t)KC * 4);
    unsigned* cmaxbits = (unsigned*)take((size_t)16 * 4);
    int*      uflag    = (int*)take((size_t)16 * 4);
    float*    dbest    = (float*)take((size_t)NW * KC * 4);
    int*      ibest    = (int*)take((size_t)NW * KC * 4);

    x2_kernel<<<(NPTS + 255) / 256, 256, 0, stream>>>(x, x2);
    init_kernel<<<KC * DIM / 256, 256, 0, stream>>>(x, seed, cA, c2A);
    totsum_kernel<<<512, 256, 0, stream>>>(x, totpart);
    totsum2_kernel<<<1, 64, 0, stream>>>(totpart, total);
    zero_kernel<<<64, 256, 0, stream>>>(excl_sum, excl_cnt, cmaxbits);

    // iteration 1 (dense)
    accum_dense<<<NB_DENSE, 512, 0, stream>>>(x, x2, cA, psums, pcnts);
    updA_kernel<<<512, 256, 0, stream>>>(psums, p2);
    updB_kernel<<<64, 256, 0, stream>>>(p2, pcnts, cB, c2B, cmaxbits + 1);

    // iterations 2..10 (screen + exact fallback; update from fp64 total)
    float *cin = cB, *cou = cA, *c2in = c2B, *c2ou = c2A;
    for (int j = 2; j <= ITERS; j++) {
        screen_kernel<<<FABLK, 256, 0, stream>>>(x, x2, cin, c2in, cmaxbits + (j - 1),
                                                 excl_sum, excl_cnt);
        update_mean<<<64, 256, 0, stream>>>(total, excl_sum, excl_cnt, cou, c2ou,
                                            cmaxbits + j);
        float* t1 = cin; cin = cou; cou = t1;
        float* t2 = c2in; c2in = c2ou; c2ou = t2;
    }
    // cin = c10, cou = c9
    ucheck_kernel<<<1, 256, 0, stream>>>(cou, cin, uflag);
    final_fast<<<FABLK, 256, 0, stream>>>(x, x2, cou, c2ou, cin, c2in, uflag, dbest, ibest);
    final_slow<<<FABLK, 256, 0, stream>>>(x, x2, cou, c2ou, cin, c2in, uflag, dbest, ibest);
    combine_kernel<<<KC, 256, 0, stream>>>(x, cin, dbest, ibest, out);
}

// Round 4
// 609.591 us; speedup vs baseline: 5.6645x; 1.3274x over previous
//
#include <hip/hip_runtime.h>

// MeanShift round 4.
// r3 post-mortem: 512-thr accum_dense spilled (FETCH 502MB/WRITE 424MB of
// scratch traffic at VGPR=128). Fixes:
//  (a) accum_dense back to 256-thr thread-owns-center, launch_bounds(256,2)
//      (256 unified VGPR+AGPR cap fits c[64]+sum[64]+P[64]+scratch), with the
//      prev-point trick: each LDS float4 read ONCE (dot of pt i + masked add
//      of pt i-1 from P regs) -> 16 ds_read_b128/pt/wave instead of 32.
//  (b) fixed-point skip restored: update_mean sets mm[j] iff exclusions!=0 or
//      c_out!=c_in bitwise; screens j>=4 early-exit when mm[j-1]==0. Exact:
//      c3 is computed by the same instructions from the same inputs as c2.

#define NPTS   200000
#define DIM    64
#define KC     256
#define ITERS  10
#define BW2    144.0f
#define CHUNK  80
#define NCHUNKS (NPTS / CHUNK)
#define NB_DENSE 256
#define NW     3125            // 200000 / 64 waves
#define FABLK  782

__global__ void x2_kernel(const float* __restrict__ x, float* __restrict__ x2) {
    int i = blockIdx.x * 256 + threadIdx.x;
    if (i >= NPTS) return;
    const float4* xi = (const float4*)(x + (size_t)i * DIM);
    float s0 = 0.f, s1 = 0.f, s2 = 0.f, s3 = 0.f;
#pragma unroll
    for (int d = 0; d < DIM / 4; d++) {
        float4 v = xi[d];
        s0 += v.x * v.x; s1 += v.y * v.y; s2 += v.z * v.z; s3 += v.w * v.w;
    }
    x2[i] = (s0 + s1) + (s2 + s3);
}

__global__ void init_kernel(const float* __restrict__ x, const int* __restrict__ seed,
                            float* __restrict__ c, float* __restrict__ c2) {
    int t = blockIdx.x * 256 + threadIdx.x;
    int k = t >> 6, d = t & 63;
    int si = seed[k];
    if ((unsigned)si >= NPTS) si = 0;
    float v = x[(size_t)si * DIM + d];
    c[t] = v;
    float s = v * v;
#pragma unroll
    for (int off = 32; off > 0; off >>= 1) s += __shfl_xor(s, off, 64);
    if (d == 0) c2[k] = s;
}

__global__ void totsum_kernel(const float* __restrict__ x, double* __restrict__ totpart) {
    __shared__ double sd[256];
    const int tid = threadIdx.x;
    double acc = 0.0;
    for (size_t f = (size_t)blockIdx.x * 256 + tid; f < (size_t)NPTS * DIM; f += 512 * 256)
        acc += (double)x[f];
    sd[tid] = acc;
    __syncthreads();
    if (tid < 64)
        totpart[(size_t)blockIdx.x * 64 + tid] =
            sd[tid] + sd[tid + 64] + sd[tid + 128] + sd[tid + 192];
}

__global__ void totsum2_kernel(const double* __restrict__ totpart, double* __restrict__ total) {
    const int d = threadIdx.x;
    double acc = 0.0;
    for (int b = 0; b < 512; b++) acc += totpart[(size_t)b * 64 + d];
    total[d] = acc;
}

__global__ void zero_kernel(float* __restrict__ excl_sum, int* __restrict__ excl_cnt,
                            unsigned* __restrict__ cmaxbits, int* __restrict__ mm) {
    int t = blockIdx.x * 256 + threadIdx.x;
    if (t < KC * DIM) excl_sum[t] = 0.f;
    if (t < KC)       excl_cnt[t] = 0;
    if (t < 16)       { cmaxbits[t] = 0u; mm[t] = 0; }
}

// ---- iteration 1: dense masked mean; 256 thr = 1 thr/center, prev-pt trick ----
__global__ __launch_bounds__(256, 2)
void accum_dense(const float* __restrict__ x, const float* __restrict__ x2,
                 const float* __restrict__ centers,
                 float* __restrict__ psums, float* __restrict__ pcnts) {
    __shared__ __align__(16) float xs[CHUNK * DIM];
    __shared__ float x2s[CHUNK];
    const int k = threadIdx.x;

    float c[DIM];
#pragma unroll
    for (int d = 0; d < DIM; d += 4) {
        float4 v = *(const float4*)(centers + k * DIM + d);
        c[d] = v.x; c[d + 1] = v.y; c[d + 2] = v.z; c[d + 3] = v.w;
    }
    float c2 = 0.f;
#pragma unroll
    for (int d = 0; d < DIM; d++) c2 += c[d] * c[d];

    float sum[DIM], P[DIM];
#pragma unroll
    for (int d = 0; d < DIM; d++) { sum[d] = 0.f; P[d] = 0.f; }
    float cnt = 0.f, mp = 0.f;

    for (int ch = blockIdx.x; ch < NCHUNKS; ch += NB_DENSE) {
        const int base = ch * CHUNK;
        __syncthreads();
        for (int t = threadIdx.x; t < CHUNK * DIM / 4; t += 256)
            ((float4*)xs)[t] = ((const float4*)(x + (size_t)base * DIM))[t];
        for (int t = threadIdx.x; t < CHUNK; t += 256)
            x2s[t] = x2[base + t];
        __syncthreads();

        for (int i = 0; i < CHUNK; i++) {
            const float4* xi = (const float4*)(xs + i * DIM);
            float a0 = 0.f, a1 = 0.f, a2 = 0.f, a3 = 0.f;
#pragma unroll
            for (int q = 0; q < 16; q++) {
                float4 v = xi[q];   // single LDS read: dot(i) + masked add(i-1)
                sum[4 * q]     += mp * P[4 * q];
                sum[4 * q + 1] += mp * P[4 * q + 1];
                sum[4 * q + 2] += mp * P[4 * q + 2];
                sum[4 * q + 3] += mp * P[4 * q + 3];
                P[4 * q] = v.x; P[4 * q + 1] = v.y;
                P[4 * q + 2] = v.z; P[4 * q + 3] = v.w;
                a0 += c[4 * q] * v.x;     a1 += c[4 * q + 1] * v.y;
                a2 += c[4 * q + 2] * v.z; a3 += c[4 * q + 3] * v.w;
            }
            float dist2 = c2 + x2s[i] - 2.f * ((a0 + a1) + (a2 + a3));
            mp = (dist2 < BW2) ? 1.f : 0.f;
            cnt += mp;
        }
    }
    // flush pending point
#pragma unroll
    for (int d = 0; d < DIM; d++) sum[d] += mp * P[d];

    float* ps = psums + (size_t)blockIdx.x * KC * DIM + k * DIM;
#pragma unroll
    for (int d = 0; d < DIM; d += 4) {
        float4 v = { sum[d], sum[d + 1], sum[d + 2], sum[d + 3] };
        *(float4*)(ps + d) = v;
    }
    pcnts[blockIdx.x * KC + k] = cnt;
}

__global__ void updA_kernel(const float* __restrict__ psums, float* __restrict__ p2) {
    const int g = blockIdx.x >> 3;
    const int h = blockIdx.x & 7;
    const int kd = g * 256 + threadIdx.x;
    float s = 0.f;
    for (int b = h * 32; b < h * 32 + 32; b++)
        s += psums[(size_t)b * KC * DIM + kd];
    p2[(size_t)h * KC * DIM + kd] = s;
}

__global__ void updB_kernel(const float* __restrict__ p2, const float* __restrict__ pcnts,
                            float* __restrict__ newc, float* __restrict__ newc2,
                            unsigned* __restrict__ cmax_out) {
    const int kd = blockIdx.x * 256 + threadIdx.x;
    const int k = kd >> 6, d = kd & 63;
    float s = 0.f;
#pragma unroll
    for (int h = 0; h < 8; h++) s += p2[(size_t)h * KC * DIM + kd];
    float cn = 0.f;
    for (int b = d; b < NB_DENSE; b += 64) cn += pcnts[b * KC + k];
#pragma unroll
    for (int off = 32; off > 0; off >>= 1) cn += __shfl_xor(cn, off, 64);
    float c = s / cn;
    newc[kd] = c;
    float q = c * c;
#pragma unroll
    for (int off = 32; off > 0; off >>= 1) q += __shfl_xor(q, off, 64);
    if (d == 0) { newc2[k] = q; atomicMax(cmax_out, __float_as_uint(q)); }
}

// ---- iters 2..10: screen (1 compare/point); inline exact fallback ----
__global__ void screen_kernel(const float* __restrict__ x, const float* __restrict__ x2,
                              const float* __restrict__ cen, const float* __restrict__ c2,
                              const unsigned* __restrict__ cmaxbits,
                              float* __restrict__ excl_sum, int* __restrict__ excl_cnt,
                              const int* __restrict__ mm_prev, int always_run) {
    if (!always_run && mm_prev[0] == 0) return;   // bit-exact fixed point reached
    int i = blockIdx.x * 256 + threadIdx.x;
    if (i >= NPTS) return;
    float cm = sqrtf(__uint_as_float(cmaxbits[0]));
    float r = 12.0f - cm - 1e-3f;
    float thr = (r > 0.f) ? r * r : -1.f;
    float x2v = x2[i];
    if (x2v < thr) return;     // |x|+max|c| < 12  =>  inside every window
    // rare exact path (expected never)
    float px[DIM];
    const float4* xr = (const float4*)(x + (size_t)i * DIM);
#pragma unroll
    for (int q = 0; q < 16; q++) {
        float4 v = xr[q];
        px[4 * q] = v.x; px[4 * q + 1] = v.y; px[4 * q + 2] = v.z; px[4 * q + 3] = v.w;
    }
    for (int k = 0; k < KC; k++) {
        const float* C = cen + k * DIM;
        float a0 = 0.f, a1 = 0.f, a2 = 0.f, a3 = 0.f;
#pragma unroll
        for (int d = 0; d < DIM; d += 4) {
            a0 = fmaf(C[d],     px[d],     a0);
            a1 = fmaf(C[d + 1], px[d + 1], a1);
            a2 = fmaf(C[d + 2], px[d + 2], a2);
            a3 = fmaf(C[d + 3], px[d + 3], a3);
        }
        float d2 = x2v + c2[k] - 2.f * ((a0 + a1) + (a2 + a3));
        if (!(d2 < BW2)) {
            atomicAdd(&excl_cnt[k], 1);
#pragma unroll 4
            for (int d = 0; d < DIM; d++) atomicAdd(&excl_sum[k * DIM + d], px[d]);
        }
    }
}

__global__ void update_mean(const double* __restrict__ total,
                            float* __restrict__ excl_sum, int* __restrict__ excl_cnt,
                            const float* __restrict__ cin,
                            float* __restrict__ cout, float* __restrict__ c2out,
                            unsigned* __restrict__ cmax_out, int* __restrict__ mm_out) {
    const int kd = blockIdx.x * 256 + threadIdx.x;
    const int k = kd >> 6, d = kd & 63;
    const float ex = excl_sum[kd];
    const int cn = excl_cnt[k];
    const float cnew = (float)((total[d] - (double)ex) / (double)(NPTS - cn));
    cout[kd] = cnew;
    float q = cnew * cnew;
#pragma unroll
    for (int off = 32; off > 0; off >>= 1) q += __shfl_xor(q, off, 64);
    if (d == 0) { c2out[k] = q; atomicMax(cmax_out, __float_as_uint(q)); }
    excl_sum[kd] = 0.f;
    if (d == 0) excl_cnt[k] = 0;
    // fixed-point detection (bitwise)
    bool same = (__float_as_uint(cnew) == __float_as_uint(cin[kd]));
    unsigned long long bl = __ballot(!same);
    if (d == 0 && (bl != 0ull || cn != 0)) atomicOr(mm_out, 1);
}

// ---- final ----
__global__ void ucheck_kernel(const float* __restrict__ c9, const float* __restrict__ c10,
                              int* __restrict__ uflag) {
    __shared__ int bad;
    const int k = threadIdx.x;     // 256
    if (k == 0) bad = 0;
    __syncthreads();
    bool ok = true;
    for (int d = 0; d < DIM; d++) {
        ok &= (__float_as_uint(c9[k * DIM + d])  == __float_as_uint(c9[d]));
        ok &= (__float_as_uint(c10[k * DIM + d]) == __float_as_uint(c10[d]));
    }
    if (!ok) atomicOr(&bad, 1);
    __syncthreads();
    if (k == 0) uflag[0] = bad ? 0 : 1;
}

__global__ __launch_bounds__(256, 2)
void final_fast(const float* __restrict__ x, const float* __restrict__ x2,
                const float* __restrict__ c9, const float* __restrict__ c29,
                const float* __restrict__ c10, const float* __restrict__ c210,
                const int* __restrict__ uflag,
                float* __restrict__ dbest, int* __restrict__ ibest) {
    if (uflag[0] == 0) return;
    __shared__ __align__(16) float s9[DIM], s10[DIM];
    __shared__ float sc[2];
    const int tid = threadIdx.x;
    if (tid < 64) s9[tid] = c9[tid];
    else if (tid < 128) s10[tid - 64] = c10[tid - 64];
    else if (tid == 128) sc[0] = c29[0];
    else if (tid == 129) sc[1] = c210[0];
    __syncthreads();

    const int i = blockIdx.x * 256 + tid;
    const bool valid = (i < NPTS);
    const int ii = valid ? i : 0;
    const float4* xr = (const float4*)(x + (size_t)ii * DIM);
    float a0 = 0.f, a1 = 0.f, a2 = 0.f, a3 = 0.f;
    float b0 = 0.f, b1 = 0.f, b2 = 0.f, b3 = 0.f;
#pragma unroll
    for (int q = 0; q < 16; q++) {
        float4 v = xr[q];
        float4 u9  = ((const float4*)s9)[q];
        float4 u10 = ((const float4*)s10)[q];
        a0 = fmaf(u9.x, v.x, a0);  a1 = fmaf(u9.y, v.y, a1);
        a2 = fmaf(u9.z, v.z, a2);  a3 = fmaf(u9.w, v.w, a3);
        b0 = fmaf(u10.x, v.x, b0); b1 = fmaf(u10.y, v.y, b1);
        b2 = fmaf(u10.z, v.z, b2); b3 = fmaf(u10.w, v.w, b3);
    }
    const float x2v = x2[ii];
    float d9 = x2v + sc[0] - 2.f * ((a0 + a1) + (a2 + a3));
    float dd = fmaxf(x2v + sc[1] - 2.f * ((b0 + b1) + (b2 + b3)), 0.f);
    float cand = (valid && d9 < BW2) ? dd : INFINITY;

    float m = cand;
#pragma unroll
    for (int off = 32; off > 0; off >>= 1) m = fminf(m, __shfl_xor(m, off, 64));
    unsigned long long bl = __ballot(cand == m);
    int sl = __ffsll(bl) - 1;
    int gi = (blockIdx.x * 256 + (tid & ~63)) + sl;   // lowest index achieving m

    const int gw = blockIdx.x * 4 + (tid >> 6);
    const int lane = tid & 63;
    if (gw < NW) {
#pragma unroll
        for (int q = 0; q < 4; q++) {
            dbest[(size_t)gw * KC + q * 64 + lane] = m;
            ibest[(size_t)gw * KC + q * 64 + lane] = gi;
        }
    }
}

__global__ __launch_bounds__(256, 2)
void final_slow(const float* __restrict__ x, const float* __restrict__ x2,
                const float* __restrict__ c9, const float* __restrict__ c29,
                const float* __restrict__ c10, const float* __restrict__ c210,
                const int* __restrict__ uflag,
                float* __restrict__ dbest, int* __restrict__ ibest) {
    if (uflag[0] != 0) return;
    const int wave = blockIdx.x * 4 + (threadIdx.x >> 6);
    if (wave >= NW) return;
    const int lane = threadIdx.x & 63;
    const int idx = wave * 64 + lane;

    float px[DIM];
    const float4* xr = (const float4*)(x + (size_t)idx * DIM);
#pragma unroll
    for (int q = 0; q < 16; q++) {
        float4 v = xr[q];
        px[4 * q] = v.x; px[4 * q + 1] = v.y; px[4 * q + 2] = v.z; px[4 * q + 3] = v.w;
    }
    const float x2v = x2[idx];

    float db[4];
    int   ib[4];
    for (int k = 0; k < KC; k++) {
        const float* A = c9  + k * DIM;
        const float* B = c10 + k * DIM;
        float a0 = 0.f, a1 = 0.f, a2 = 0.f, a3 = 0.f;
        float b0 = 0.f, b1 = 0.f, b2 = 0.f, b3 = 0.f;
#pragma unroll
        for (int d = 0; d < DIM; d += 4) {
            a0 = fmaf(A[d],     px[d],     a0);
            a1 = fmaf(A[d + 1], px[d + 1], a1);
            a2 = fmaf(A[d + 2], px[d + 2], a2);
            a3 = fmaf(A[d + 3], px[d + 3], a3);
            b0 = fmaf(B[d],     px[d],     b0);
            b1 = fmaf(B[d + 1], px[d + 1], b1);
            b2 = fmaf(B[d + 2], px[d + 2], b2);
            b3 = fmaf(B[d + 3], px[d + 3], b3);
        }
        float d9 = x2v + c29[k] - 2.f * ((a0 + a1) + (a2 + a3));
        float dd = x2v + c210[k] - 2.f * ((b0 + b1) + (b2 + b3));
        dd = fmaxf(dd, 0.f);
        float cand = (d9 < BW2) ? dd : INFINITY;
        float m = cand;
#pragma unroll
        for (int off = 32; off > 0; off >>= 1) m = fminf(m, __shfl_xor(m, off, 64));
        unsigned long long bl = __ballot(cand == m);
        int sl = __ffsll(bl) - 1;
        int gi = wave * 64 + sl;
        int qq = k >> 6;
        if ((k & 63) == lane) { db[qq] = m; ib[qq] = gi; }
    }
#pragma unroll
    for (int q = 0; q < 4; q++) {
        dbest[(size_t)wave * KC + q * 64 + lane] = db[q];
        ibest[(size_t)wave * KC + q * 64 + lane] = ib[q];
    }
}

__global__ void combine_kernel(const float* __restrict__ x, const float* __restrict__ c10,
                               const float* __restrict__ dbest, const int* __restrict__ ibest,
                               float* __restrict__ out) {
    __shared__ float sd[256];
    __shared__ int   si[256];
    const int k = blockIdx.x;
    const int t = threadIdx.x;
    float bd = INFINITY;
    int   bi = 0x7FFFFFFF;
    for (int w = t; w < NW; w += 256) {
        float d = dbest[(size_t)w * KC + k];
        int   i = ibest[(size_t)w * KC + k];
        if (d < bd || (d == bd && i < bi)) { bd = d; bi = i; }
    }
    sd[t] = bd; si[t] = bi;
    __syncthreads();
    for (int s = 128; s > 0; s >>= 1) {
        if (t < s) {
            float d = sd[t + s]; int i = si[t + s];
            if (d < sd[t] || (d == sd[t] && i < si[t])) { sd[t] = d; si[t] = i; }
        }
        __syncthreads();
    }
    bi = si[0];
    if ((unsigned)bi >= NPTS) bi = 0;
    if (t < DIM) {
        out[k * DIM + t] = c10[k * DIM + t];
        out[KC * DIM + k * DIM + t] = x[(size_t)bi * DIM + t];
    }
    if (t == 0) out[2 * KC * DIM + k] = (float)bi;
}

extern "C" void kernel_launch(void* const* d_in, const int* in_sizes, int n_in,
                              void* d_out, int out_size, void* d_ws, size_t ws_size,
                              hipStream_t stream) {
    const float* x    = (const float*)d_in[0];
    const int*   seed = (const int*)d_in[1];
    float*       out  = (float*)d_out;

    char* w = (char*)d_ws;
    auto take = [&](size_t bytes) { char* p = w; w += (bytes + 511) & ~(size_t)511; return p; };
    float*    x2       = (float*)take((size_t)NPTS * 4);
    float*    cA       = (float*)take((size_t)KC * DIM * 4);
    float*    cB       = (float*)take((size_t)KC * DIM * 4);
    float*    c2A      = (float*)take((size_t)KC * 4);
    float*    c2B      = (float*)take((size_t)KC * 4);
    double*   total    = (double*)take((size_t)DIM * 8);
    double*   totpart  = (double*)take((size_t)512 * DIM * 8);
    float*    psums    = (float*)take((size_t)NB_DENSE * KC * DIM * 4);
    float*    pcnts    = (float*)take((size_t)NB_DENSE * KC * 4);
    float*    p2       = (float*)take((size_t)8 * KC * DIM * 4);
    float*    excl_sum = (float*)take((size_t)KC * DIM * 4);
    int*      excl_cnt = (int*)take((size_t)KC * 4);
    unsigned* cmaxbits = (unsigned*)take((size_t)16 * 4);
    int*      mm       = (int*)take((size_t)16 * 4);
    int*      uflag    = (int*)take((size_t)16 * 4);
    float*    dbest    = (float*)take((size_t)NW * KC * 4);
    int*      ibest    = (int*)take((size_t)NW * KC * 4);

    x2_kernel<<<(NPTS + 255) / 256, 256, 0, stream>>>(x, x2);
    init_kernel<<<KC * DIM / 256, 256, 0, stream>>>(x, seed, cA, c2A);
    totsum_kernel<<<512, 256, 0, stream>>>(x, totpart);
    totsum2_kernel<<<1, 64, 0, stream>>>(totpart, total);
    zero_kernel<<<64, 256, 0, stream>>>(excl_sum, excl_cnt, cmaxbits, mm);

    // iteration 1 (dense)
    accum_dense<<<NB_DENSE, 256, 0, stream>>>(x, x2, cA, psums, pcnts);
    updA_kernel<<<512, 256, 0, stream>>>(psums, p2);
    updB_kernel<<<64, 256, 0, stream>>>(p2, pcnts, cB, c2B, cmaxbits + 1);

    // iterations 2..10 (screen + exact fallback; skip after bitwise fixed point)
    float *cin = cB, *cou = cA, *c2in = c2B, *c2ou = c2A;
    for (int j = 2; j <= ITERS; j++) {
        screen_kernel<<<FABLK, 256, 0, stream>>>(x, x2, cin, c2in, cmaxbits + (j - 1),
                                                 excl_sum, excl_cnt,
                                                 mm + (j - 1), (j <= 3) ? 1 : 0);
        update_mean<<<64, 256, 0, stream>>>(total, excl_sum, excl_cnt, cin, cou, c2ou,
                                            cmaxbits + j, mm + j);
        float* t1 = cin; cin = cou; cou = t1;
        float* t2 = c2in; c2in = c2ou; c2ou = t2;
    }
    // cin = c10, cou = c9
    ucheck_kernel<<<1, 256, 0, stream>>>(cou, cin, uflag);
    final_fast<<<FABLK, 256, 0, stream>>>(x, x2, cou, c2ou, cin, c2in, uflag, dbest, ibest);
    final_slow<<<FABLK, 256, 0, stream>>>(x, x2, cou, c2ou, cin, c2in, uflag, dbest, ibest);
    combine_kernel<<<KC, 256, 0, stream>>>(x, cin, dbest, ibest, out);
}